// Round 5
// baseline (787.424 us; speedup 1.0000x reference)
//
#include <hip/hip_runtime.h>
#include <math.h>

#define BB 4
#define LL 1024
#define DD 1024
#define KK 20
#define CC 21
#define LC (LL * CC)          // 21504 floats per (b, i) output row-panel
#define NQ (LC / 4)           // 5376 float4 per panel

typedef float vf4 __attribute__((ext_vector_type(4)));   // native vec for NT store

__device__ __forceinline__ float wave_reduce_sum(float v) {
    #pragma unroll
    for (int off = 1; off < 64; off <<= 1)
        v += __shfl_xor(v, off, 64);
    return v;
}

// ---------------------------------------------------------------------------
// Kernel 0: zd[k,c] = dic[k,:] . Wz_w[c,:] + Wz_b[c]       (e in [0,420))
//           M [k,c] = dic[k,:] . cs_w[c, D:2D]             (e in [420,840))
// ---------------------------------------------------------------------------
__global__ __launch_bounds__(64) void k0_zdM(
    const float* __restrict__ dic,
    const float* __restrict__ Wz_w, const float* __restrict__ Wz_b,
    const float* __restrict__ cs_w,
    float* __restrict__ zd, float* __restrict__ M)
{
    int e = blockIdx.x;                 // 0..2*K*C-1
    int lane = threadIdx.x;
    bool isM = (e >= KK * CC);
    int e2 = isM ? e - KK * CC : e;
    int k = e2 / CC, c = e2 % CC;
    const float* a = dic + k * DD;
    const float* w = isM ? (cs_w + (size_t)c * (2 * DD) + DD) : (Wz_w + c * DD);
    float p = 0.f;
    #pragma unroll
    for (int i = 0; i < DD / 64; ++i) {
        int d = lane + 64 * i;
        p += a[d] * w[d];
    }
    p = wave_reduce_sum(p);
    if (lane == 0) {
        if (isM) M[e2] = p;
        else     zd[e2] = p + Wz_b[c];
    }
}

// ---------------------------------------------------------------------------
// Kernel 1 (DIAGNOSTIC: body repeated `rep` times, idempotent).
// ---------------------------------------------------------------------------
__global__ __launch_bounds__(64) void k1_rows(
    const float* __restrict__ x,
    const float* __restrict__ prior,
    const float* __restrict__ Wy_w, const float* __restrict__ Wy_b,
    const float* __restrict__ cs_w, const float* __restrict__ cs_b,
    const float* __restrict__ zd, const float* __restrict__ M,
    float* __restrict__ ly_ws, float* __restrict__ lz_ws, int rep)
{
    int lane = threadIdx.x;
    int r0 = blockIdx.x * 4;            // 1024 blocks * 4 rows

    __shared__ float zds[KK * CC];
    __shared__ float Ms[KK * CC];
    for (int i = lane; i < KK * CC; i += 64) {
        zds[i] = zd[i];
        Ms[i]  = M[i];
    }

    float4 yv[4][4];                    // lane's 16 floats per row, as float4
    #pragma unroll
    for (int r = 0; r < 4; ++r) {
        const float4* y4 = reinterpret_cast<const float4*>(x + (size_t)(r0 + r) * DD);
        #pragma unroll
        for (int i = 0; i < 4; ++i) yv[r][i] = y4[lane + 64 * i];
    }
    __syncthreads();

    int myrow = lane & 3;

    for (int rp = 0; rp < rep; ++rp) {
        asm volatile("" ::: "memory");      // defeat cross-rep CSE
        float myw[CC], myly[CC];

        #pragma unroll
        for (int c = 0; c < CC; ++c) {
            const float4* w14 = reinterpret_cast<const float4*>(Wy_w + (size_t)c * DD);
            const float4* w24 = reinterpret_cast<const float4*>(cs_w + (size_t)c * (2 * DD));
            float p1[4] = {0.f, 0.f, 0.f, 0.f};
            float p2[4] = {0.f, 0.f, 0.f, 0.f};
            #pragma unroll
            for (int i = 0; i < 4; ++i) {
                float4 wa = w14[lane + 64 * i];
                float4 wb = w24[lane + 64 * i];
                #pragma unroll
                for (int r = 0; r < 4; ++r) {
                    p1[r] += yv[r][i].x * wa.x + yv[r][i].y * wa.y
                           + yv[r][i].z * wa.z + yv[r][i].w * wa.w;
                    p2[r] += yv[r][i].x * wb.x + yv[r][i].y * wb.y
                           + yv[r][i].z * wb.z + yv[r][i].w * wb.w;
                }
            }
            #pragma unroll
            for (int r = 0; r < 4; ++r) {
                p1[r] = wave_reduce_sum(p1[r]);
                p2[r] = wave_reduce_sum(p2[r]);
            }
            float s1 = p1[0], s2 = p2[0];
            if (myrow == 1) { s1 = p1[1]; s2 = p2[1]; }
            if (myrow == 2) { s1 = p1[2]; s2 = p2[2]; }
            if (myrow == 3) { s1 = p1[3]; s2 = p2[3]; }
            myw[c]  = s1 + Wy_b[c];
            myly[c] = s2;
        }

        const float scale = 0.2182178902359924f;   // 1/sqrt(21)
        float s[KK];
        float m = -1e30f;
        #pragma unroll
        for (int k = 0; k < KK; ++k) {
            float t = 0.f;
            #pragma unroll
            for (int c = 0; c < CC; ++c) t += myw[c] * zds[k * CC + c];
            s[k] = t * scale;
            m = fmaxf(m, s[k]);
        }
        float sum = 0.f;
        #pragma unroll
        for (int k = 0; k < KK; ++k) { s[k] = expf(s[k] - m); sum += s[k]; }
        float inv = 1.f / sum;
        float wk[KK];
        #pragma unroll
        for (int k = 0; k < KK; ++k) wk[k] = s[k] * inv * prior[k];

        float mlz[CC];
        #pragma unroll
        for (int c = 0; c < CC; ++c) {
            float t = cs_b[c];
            #pragma unroll
            for (int k = 0; k < KK; ++k) t += wk[k] * Ms[k * CC + c];
            mlz[c] = t;
        }

        if (lane < 4) {
            float* lyp = ly_ws + (size_t)(r0 + lane) * CC;
            float* lzp = lz_ws + (size_t)(r0 + lane) * CC;
            #pragma unroll
            for (int c = 0; c < CC; ++c) { lyp[c] = myly[c]; lzp[c] = mlz[c]; }
        }
    }
}

// ---------------------------------------------------------------------------
// Kernel 2 (DIAGNOSTIC: store sweep repeated `rep` times, idempotent).
// ---------------------------------------------------------------------------
__global__ __launch_bounds__(512) void k2_outer(
    const float* __restrict__ ly_ws, const float* __restrict__ lz_ws,
    float* __restrict__ out, int rep)
{
    int tid = threadIdx.x;
    int blk = blockIdx.x;               // 0..1023
    int b  = blk >> 8;                  // 256 blocks per image
    int i0 = (blk & 255) << 2;          // * 4 panels

    // lyp4[i][g] = ( ly[(4g)%21], ly[(4g+1)%21], ly[(4g+2)%21], ly[(4g+3)%21] )
    __shared__ vf4 lyp4[4 * CC];
    {
        float* lyp = reinterpret_cast<float*>(lyp4);
        if (tid < 4 * 84) {
            int i = tid / 84, f = tid % 84;
            lyp[i * 84 + f] = ly_ws[(size_t)(b * LL + i0 + i) * CC + (f % 21)];
        }
    }

    const float* lzp = lz_ws + (size_t)b * LC;
    vf4 lzv[11];
    #pragma unroll
    for (int it = 0; it < 11; ++it) {
        int idx = tid + it * 512;
        if (idx < NQ) {
            lzv[it] = *reinterpret_cast<const vf4*>(lzp + (size_t)idx * 4);
        } else {
            lzv[it] = (vf4){0.f, 0.f, 0.f, 0.f};
        }
    }
    __syncthreads();

    int g0 = tid % 21;                  // (tid + it*512) % 21 steps by +8 mod 21

    for (int rp = 0; rp < rep; ++rp) {
        asm volatile("" ::: "memory");      // defeat cross-rep store elision
        #pragma unroll
        for (int i = 0; i < 4; ++i) {
            float* op = out + (size_t)(b * LL + i0 + i) * LC;
            const vf4* lyp_i = lyp4 + i * CC;
            int g = g0;
            #pragma unroll
            for (int it = 0; it < 11; ++it) {
                int idx = tid + it * 512;
                if (idx < NQ) {
                    vf4 o = lzv[it] + lyp_i[g];
                    __builtin_nontemporal_store(o, reinterpret_cast<vf4*>(op + (size_t)idx * 4));
                }
                g += 8; if (g >= 21) g -= 21;
            }
        }
    }
}

extern "C" void kernel_launch(void* const* d_in, const int* in_sizes, int n_in,
                              void* d_out, int out_size, void* d_ws, size_t ws_size,
                              hipStream_t stream)
{
    const float* x     = (const float*)d_in[0];
    const float* dic   = (const float*)d_in[1];
    const float* prior = (const float*)d_in[2];
    const float* Wy_w  = (const float*)d_in[3];
    const float* Wy_b  = (const float*)d_in[4];
    const float* Wz_w  = (const float*)d_in[5];
    const float* Wz_b  = (const float*)d_in[6];
    const float* cs_w  = (const float*)d_in[7];
    const float* cs_b  = (const float*)d_in[8];
    float* out = (float*)d_out;

    float* ws = (float*)d_ws;
    float* zd = ws;                       // 420 floats
    float* M  = ws + 512;                 // 420 floats
    float* ly = ws + 1024;                // B*L*C = 86016 floats
    float* lz = ly + BB * LL * CC;        // 86016 floats

    k0_zdM <<<dim3(2 * KK * CC), dim3(64),  0, stream>>>(dic, Wz_w, Wz_b, cs_w, zd, M);
    k1_rows<<<dim3(BB * LL / 4), dim3(64),  0, stream>>>(x, prior, Wy_w, Wy_b, cs_w, cs_b,
                                                         zd, M, ly, lz, 8);
    k2_outer<<<dim3(BB * LL / 4), dim3(512), 0, stream>>>(ly, lz, out, 6);
}

// Round 6
// 286.240 us; speedup vs baseline: 2.7509x; 2.7509x over previous
//
#include <hip/hip_runtime.h>
#include <math.h>

#define BB 4
#define LL 1024
#define DD 1024
#define KK 20
#define CC 21
#define LC (LL * CC)          // 21504 floats per (b, i) output row-panel
#define NQ (LC / 4)           // 5376 float4 per panel

typedef float vf4 __attribute__((ext_vector_type(4)));   // native vec for NT store

#define DOT4(a, b) ((a).x*(b).x + (a).y*(b).y + (a).z*(b).z + (a).w*(b).w)

__device__ __forceinline__ float wave_reduce_sum(float v) {
    #pragma unroll
    for (int off = 1; off < 64; off <<= 1)
        v += __shfl_xor(v, off, 64);
    return v;
}

// ---------------------------------------------------------------------------
// Kernel 0: zd[k,c] = dic[k,:] . Wz_w[c,:] + Wz_b[c]       (e in [0,420))
//           M [k,c] = dic[k,:] . cs_w[c, D:2D]             (e in [420,840))
// ---------------------------------------------------------------------------
__global__ __launch_bounds__(64) void k0_zdM(
    const float* __restrict__ dic,
    const float* __restrict__ Wz_w, const float* __restrict__ Wz_b,
    const float* __restrict__ cs_w,
    float* __restrict__ zd, float* __restrict__ M)
{
    int e = blockIdx.x;                 // 0..2*K*C-1
    int lane = threadIdx.x;
    bool isM = (e >= KK * CC);
    int e2 = isM ? e - KK * CC : e;
    int k = e2 / CC, c = e2 % CC;
    const float* a = dic + k * DD;
    const float* w = isM ? (cs_w + (size_t)c * (2 * DD) + DD) : (Wz_w + c * DD);
    float p = 0.f;
    #pragma unroll
    for (int i = 0; i < DD / 64; ++i) {
        int d = lane + 64 * i;
        p += a[d] * w[d];
    }
    p = wave_reduce_sum(p);
    if (lane == 0) {
        if (isM) M[e2] = p;
        else     zd[e2] = p + Wz_b[c];
    }
}

// ---------------------------------------------------------------------------
// Kernel 1 (rebuilt): 2 rows per single-wave block, 2048 blocks (8 waves/CU).
// No shfl butterflies: per-lane partial dots (84 regs) -> LDS transpose
// ([64][45], stride 45 => <=2-way banks) -> per-lane column sums.
// Softmax: half-wave per row, redundant across 32 lanes (cheap VALU).
// ---------------------------------------------------------------------------
__global__ __launch_bounds__(64) void k1_rows(
    const float* __restrict__ x,
    const float* __restrict__ prior,
    const float* __restrict__ Wy_w, const float* __restrict__ Wy_b,
    const float* __restrict__ cs_w, const float* __restrict__ cs_b,
    const float* __restrict__ zd, const float* __restrict__ M,
    float* __restrict__ ly_ws, float* __restrict__ lz_ws)
{
    const int lane = threadIdx.x;
    const int r0 = blockIdx.x * 2;

    __shared__ float zds[KK * CC];
    __shared__ float Ms[KK * CC];
    __shared__ float pr[KK];
    __shared__ float bias[2 * CC];      // [0..20]=Wy_b, [21..41]=cs_b
    __shared__ float tr[64 * 45];       // transpose buffer, stride 45
    __shared__ float fin[2][48];        // reduced outputs per row

    for (int i = lane; i < KK * CC; i += 64) { zds[i] = zd[i]; Ms[i] = M[i]; }
    if (lane < KK) pr[lane] = prior[lane];
    if (lane < CC) { bias[lane] = Wy_b[lane]; bias[CC + lane] = cs_b[lane]; }

    // x rows in registers (coalesced float4)
    const float4* xA4 = reinterpret_cast<const float4*>(x + (size_t)r0 * DD);
    const float4* xB4 = reinterpret_cast<const float4*>(x + (size_t)(r0 + 1) * DD);
    float4 xA[4], xB[4];
    #pragma unroll
    for (int i = 0; i < 4; ++i) { xA[i] = xA4[lane + 64 * i]; xB[i] = xB4[lane + 64 * i]; }

    // 84 per-lane partials: [0..20] yw, [21..41] ly, for rows A and B
    float pA[2 * CC], pB[2 * CC];
    #pragma unroll
    for (int c = 0; c < CC; ++c) {
        const float4* w4 = reinterpret_cast<const float4*>(Wy_w + (size_t)c * DD);
        float sA = 0.f, sB = 0.f;
        #pragma unroll
        for (int i = 0; i < 4; ++i) {
            float4 w = w4[lane + 64 * i];
            sA += DOT4(xA[i], w);
            sB += DOT4(xB[i], w);
        }
        pA[c] = sA; pB[c] = sB;
    }
    #pragma unroll
    for (int c = 0; c < CC; ++c) {
        const float4* w4 = reinterpret_cast<const float4*>(cs_w + (size_t)c * (2 * DD));
        float sA = 0.f, sB = 0.f;
        #pragma unroll
        for (int i = 0; i < 4; ++i) {
            float4 w = w4[lane + 64 * i];
            sA += DOT4(xA[i], w);
            sB += DOT4(xB[i], w);
        }
        pA[CC + c] = sA; pB[CC + c] = sB;
    }

    // ---- transpose-reduce row A ----
    #pragma unroll
    for (int c = 0; c < 2 * CC; ++c) tr[lane * 45 + c] = pA[c];
    __syncthreads();
    if (lane < 2 * CC) {
        float a0 = 0.f, a1 = 0.f, a2 = 0.f, a3 = 0.f;
        #pragma unroll
        for (int j = 0; j < 64; j += 4) {
            a0 += tr[(j + 0) * 45 + lane];
            a1 += tr[(j + 1) * 45 + lane];
            a2 += tr[(j + 2) * 45 + lane];
            a3 += tr[(j + 3) * 45 + lane];
        }
        float v = (a0 + a1) + (a2 + a3);
        if (lane < CC) v += bias[lane];         // Wy_b on yw outputs only
        fin[0][lane] = v;
    }
    __syncthreads();

    // ---- transpose-reduce row B ----
    #pragma unroll
    for (int c = 0; c < 2 * CC; ++c) tr[lane * 45 + c] = pB[c];
    __syncthreads();
    if (lane < 2 * CC) {
        float a0 = 0.f, a1 = 0.f, a2 = 0.f, a3 = 0.f;
        #pragma unroll
        for (int j = 0; j < 64; j += 4) {
            a0 += tr[(j + 0) * 45 + lane];
            a1 += tr[(j + 1) * 45 + lane];
            a2 += tr[(j + 2) * 45 + lane];
            a3 += tr[(j + 3) * 45 + lane];
        }
        float v = (a0 + a1) + (a2 + a3);
        if (lane < CC) v += bias[lane];
        fin[1][lane] = v;
    }
    __syncthreads();

    // ---- softmax + lz: lanes 0..31 -> row0, lanes 32..63 -> row1 ----
    const int row = lane >> 5;
    const int cc  = lane & 31;
    const float* f = &fin[row][0];

    const float scale = 0.21821789023599238f;   // 1/sqrt(21)
    float s[KK];
    float m = -1e30f;
    #pragma unroll
    for (int k = 0; k < KK; ++k) {
        float t = 0.f;
        #pragma unroll
        for (int c = 0; c < CC; ++c) t += f[c] * zds[k * CC + c];
        s[k] = t * scale;
        m = fmaxf(m, s[k]);
    }
    float sum = 0.f;
    #pragma unroll
    for (int k = 0; k < KK; ++k) { s[k] = expf(s[k] - m); sum += s[k]; }
    float inv = 1.f / sum;

    if (cc < CC) {
        float lzv = bias[CC + cc];              // cs_b
        #pragma unroll
        for (int k = 0; k < KK; ++k) lzv += s[k] * inv * pr[k] * Ms[k * CC + cc];
        size_t r = (size_t)(r0 + row);
        ly_ws[r * CC + cc] = f[CC + cc];
        lz_ws[r * CC + cc] = lzv;
    }
}

// ---------------------------------------------------------------------------
// Kernel 2: outer-sum write (measured at write roofline ~6.5 TB/s) — unchanged.
// ---------------------------------------------------------------------------
__global__ __launch_bounds__(512) void k2_outer(
    const float* __restrict__ ly_ws, const float* __restrict__ lz_ws,
    float* __restrict__ out)
{
    int tid = threadIdx.x;
    int blk = blockIdx.x;               // 0..1023
    int b  = blk >> 8;                  // 256 blocks per image
    int i0 = (blk & 255) << 2;          // * 4 panels

    __shared__ vf4 lyp4[4 * CC];
    {
        float* lyp = reinterpret_cast<float*>(lyp4);
        if (tid < 4 * 84) {
            int i = tid / 84, f = tid % 84;
            lyp[i * 84 + f] = ly_ws[(size_t)(b * LL + i0 + i) * CC + (f % 21)];
        }
    }

    const float* lzp = lz_ws + (size_t)b * LC;
    vf4 lzv[11];
    #pragma unroll
    for (int it = 0; it < 11; ++it) {
        int idx = tid + it * 512;
        if (idx < NQ) {
            lzv[it] = *reinterpret_cast<const vf4*>(lzp + (size_t)idx * 4);
        } else {
            lzv[it] = (vf4){0.f, 0.f, 0.f, 0.f};
        }
    }
    __syncthreads();

    int g0 = tid % 21;                  // (tid + it*512) % 21 steps by +8 mod 21

    #pragma unroll
    for (int i = 0; i < 4; ++i) {
        float* op = out + (size_t)(b * LL + i0 + i) * LC;
        const vf4* lyp_i = lyp4 + i * CC;
        int g = g0;
        #pragma unroll
        for (int it = 0; it < 11; ++it) {
            int idx = tid + it * 512;
            if (idx < NQ) {
                vf4 o = lzv[it] + lyp_i[g];
                __builtin_nontemporal_store(o, reinterpret_cast<vf4*>(op + (size_t)idx * 4));
            }
            g += 8; if (g >= 21) g -= 21;
        }
    }
}

extern "C" void kernel_launch(void* const* d_in, const int* in_sizes, int n_in,
                              void* d_out, int out_size, void* d_ws, size_t ws_size,
                              hipStream_t stream)
{
    const float* x     = (const float*)d_in[0];
    const float* dic   = (const float*)d_in[1];
    const float* prior = (const float*)d_in[2];
    const float* Wy_w  = (const float*)d_in[3];
    const float* Wy_b  = (const float*)d_in[4];
    const float* Wz_w  = (const float*)d_in[5];
    const float* Wz_b  = (const float*)d_in[6];
    const float* cs_w  = (const float*)d_in[7];
    const float* cs_b  = (const float*)d_in[8];
    float* out = (float*)d_out;

    float* ws = (float*)d_ws;
    float* zd = ws;                       // 420 floats
    float* M  = ws + 512;                 // 420 floats
    float* ly = ws + 1024;                // B*L*C = 86016 floats
    float* lz = ly + BB * LL * CC;        // 86016 floats

    k0_zdM <<<dim3(2 * KK * CC), dim3(64),  0, stream>>>(dic, Wz_w, Wz_b, cs_w, zd, M);
    k1_rows<<<dim3(BB * LL / 2), dim3(64),  0, stream>>>(x, prior, Wy_w, Wy_b, cs_w, cs_b,
                                                         zd, M, ly, lz);
    k2_outer<<<dim3(BB * LL / 4), dim3(512), 0, stream>>>(ly, lz, out);
}

// Round 7
// 105.420 us; speedup vs baseline: 7.4694x; 2.7152x over previous
//
#include <hip/hip_runtime.h>
#include <math.h>

#define BB 4
#define LL 1024
#define DD 1024
#define KK 20
#define CC 21
#define LC (LL * CC)          // 21504 floats per (b, i) output row-panel
#define NQ (LC / 4)           // 5376 float4 per panel

typedef float vf4 __attribute__((ext_vector_type(4)));   // native vec for NT store

#define DOT4(a, b) ((a).x*(b).x + (a).y*(b).y + (a).z*(b).z + (a).w*(b).w)

__device__ __forceinline__ float wave_reduce_sum(float v) {
    #pragma unroll
    for (int off = 1; off < 64; off <<= 1)
        v += __shfl_xor(v, off, 64);
    return v;
}

// ---------------------------------------------------------------------------
// Kernel 0: zd[k,c] = dic[k,:] . Wz_w[c,:] + Wz_b[c]       (e in [0,420))
//           M [k,c] = dic[k,:] . cs_w[c, D:2D]             (e in [420,840))
// ---------------------------------------------------------------------------
__global__ __launch_bounds__(64) void k0_zdM(
    const float* __restrict__ dic,
    const float* __restrict__ Wz_w, const float* __restrict__ Wz_b,
    const float* __restrict__ cs_w,
    float* __restrict__ zd, float* __restrict__ M)
{
    int e = blockIdx.x;                 // 0..2*K*C-1
    int lane = threadIdx.x;
    bool isM = (e >= KK * CC);
    int e2 = isM ? e - KK * CC : e;
    int k = e2 / CC, c = e2 % CC;
    const float* a = dic + k * DD;
    const float* w = isM ? (cs_w + (size_t)c * (2 * DD) + DD) : (Wz_w + c * DD);
    float p = 0.f;
    #pragma unroll
    for (int i = 0; i < DD / 64; ++i) {
        int d = lane + 64 * i;
        p += a[d] * w[d];
    }
    p = wave_reduce_sum(p);
    if (lane == 0) {
        if (isM) M[e2] = p;
        else     zd[e2] = p + Wz_b[c];
    }
}

// ---------------------------------------------------------------------------
// Kernel 1: 2 rows per single-wave block, 2048 blocks.
// Per-c dot partial -> IMMEDIATE ds_write (no register arrays, no spills).
// trA/trB [64][43]: write phase 11*lane+c mod 32 hits all banks (free);
// reduce phase consecutive lanes -> <=2-way (free). One sync, then 42-lane
// column reduce per row, then half-wave softmax (row = lane>>5).
// ---------------------------------------------------------------------------
__global__ __launch_bounds__(64) void k1_rows(
    const float* __restrict__ x,
    const float* __restrict__ prior,
    const float* __restrict__ Wy_w, const float* __restrict__ Wy_b,
    const float* __restrict__ cs_w, const float* __restrict__ cs_b,
    const float* __restrict__ zd, const float* __restrict__ M,
    float* __restrict__ ly_ws, float* __restrict__ lz_ws)
{
    const int lane = threadIdx.x;
    const int r0 = blockIdx.x * 2;

    __shared__ float zds[KK * CC];
    __shared__ float Ms[KK * CC];
    __shared__ float pr[KK];
    __shared__ float bias[2 * CC];      // [0..20]=Wy_b, [21..41]=cs_b
    __shared__ float trA[64 * 43];      // row-A partials, stride 43
    __shared__ float trB[64 * 43];      // row-B partials
    __shared__ float fin[2][48];        // reduced outputs per row

    for (int i = lane; i < KK * CC; i += 64) { zds[i] = zd[i]; Ms[i] = M[i]; }
    if (lane < KK) pr[lane] = prior[lane];
    if (lane < CC) { bias[lane] = Wy_b[lane]; bias[CC + lane] = cs_b[lane]; }

    // x rows in registers (coalesced float4)
    const float4* xA4 = reinterpret_cast<const float4*>(x + (size_t)r0 * DD);
    const float4* xB4 = reinterpret_cast<const float4*>(x + (size_t)(r0 + 1) * DD);
    float4 xA[4], xB[4];
    #pragma unroll
    for (int i = 0; i < 4; ++i) { xA[i] = xA4[lane + 64 * i]; xB[i] = xB4[lane + 64 * i]; }

    // 42 dual-row dot partials, flushed to LDS immediately (cols 0..20: Wy_w)
    #pragma unroll
    for (int c = 0; c < CC; ++c) {
        const float4* w4 = reinterpret_cast<const float4*>(Wy_w + (size_t)c * DD);
        float sA = 0.f, sB = 0.f;
        #pragma unroll
        for (int i = 0; i < 4; ++i) {
            float4 w = w4[lane + 64 * i];
            sA += DOT4(xA[i], w);
            sB += DOT4(xB[i], w);
        }
        trA[lane * 43 + c] = sA;
        trB[lane * 43 + c] = sB;
    }
    // cols 21..41: cs_w first halves
    #pragma unroll
    for (int c = 0; c < CC; ++c) {
        const float4* w4 = reinterpret_cast<const float4*>(cs_w + (size_t)c * (2 * DD));
        float sA = 0.f, sB = 0.f;
        #pragma unroll
        for (int i = 0; i < 4; ++i) {
            float4 w = w4[lane + 64 * i];
            sA += DOT4(xA[i], w);
            sB += DOT4(xB[i], w);
        }
        trA[lane * 43 + CC + c] = sA;
        trB[lane * 43 + CC + c] = sB;
    }
    __syncthreads();

    // column reduce: 42 lanes, rows A then B
    if (lane < 2 * CC) {
        float a0 = 0.f, a1 = 0.f, a2 = 0.f, a3 = 0.f;
        #pragma unroll
        for (int j = 0; j < 64; j += 4) {
            a0 += trA[(j + 0) * 43 + lane];
            a1 += trA[(j + 1) * 43 + lane];
            a2 += trA[(j + 2) * 43 + lane];
            a3 += trA[(j + 3) * 43 + lane];
        }
        float v = (a0 + a1) + (a2 + a3);
        if (lane < CC) v += bias[lane];
        fin[0][lane] = v;

        a0 = a1 = a2 = a3 = 0.f;
        #pragma unroll
        for (int j = 0; j < 64; j += 4) {
            a0 += trB[(j + 0) * 43 + lane];
            a1 += trB[(j + 1) * 43 + lane];
            a2 += trB[(j + 2) * 43 + lane];
            a3 += trB[(j + 3) * 43 + lane];
        }
        v = (a0 + a1) + (a2 + a3);
        if (lane < CC) v += bias[lane];
        fin[1][lane] = v;
    }
    __syncthreads();

    // ---- softmax + lz: lanes 0..31 -> row0, lanes 32..63 -> row1 ----
    const int row = lane >> 5;
    const int cc  = lane & 31;
    const float* f = &fin[row][0];

    const float scale = 0.21821789023599238f;   // 1/sqrt(21)
    float s[KK];
    float m = -1e30f;
    #pragma unroll
    for (int k = 0; k < KK; ++k) {
        float t = 0.f;
        #pragma unroll
        for (int c = 0; c < CC; ++c) t += f[c] * zds[k * CC + c];
        s[k] = t * scale;
        m = fmaxf(m, s[k]);
    }
    float sum = 0.f;
    #pragma unroll
    for (int k = 0; k < KK; ++k) { s[k] = expf(s[k] - m); sum += s[k]; }
    float inv = 1.f / sum;

    if (cc < CC) {
        float lzv = bias[CC + cc];              // cs_b
        #pragma unroll
        for (int k = 0; k < KK; ++k) lzv += s[k] * inv * pr[k] * Ms[k * CC + cc];
        size_t r = (size_t)(r0 + row);
        ly_ws[r * CC + cc] = f[CC + cc];
        lz_ws[r * CC + cc] = lzv;
    }
}

// ---------------------------------------------------------------------------
// Kernel 2: outer-sum write (measured at write roofline ~6.5 TB/s) — unchanged.
// ---------------------------------------------------------------------------
__global__ __launch_bounds__(512) void k2_outer(
    const float* __restrict__ ly_ws, const float* __restrict__ lz_ws,
    float* __restrict__ out)
{
    int tid = threadIdx.x;
    int blk = blockIdx.x;               // 0..1023
    int b  = blk >> 8;                  // 256 blocks per image
    int i0 = (blk & 255) << 2;          // * 4 panels

    __shared__ vf4 lyp4[4 * CC];
    {
        float* lyp = reinterpret_cast<float*>(lyp4);
        if (tid < 4 * 84) {
            int i = tid / 84, f = tid % 84;
            lyp[i * 84 + f] = ly_ws[(size_t)(b * LL + i0 + i) * CC + (f % 21)];
        }
    }

    const float* lzp = lz_ws + (size_t)b * LC;
    vf4 lzv[11];
    #pragma unroll
    for (int it = 0; it < 11; ++it) {
        int idx = tid + it * 512;
        if (idx < NQ) {
            lzv[it] = *reinterpret_cast<const vf4*>(lzp + (size_t)idx * 4);
        } else {
            lzv[it] = (vf4){0.f, 0.f, 0.f, 0.f};
        }
    }
    __syncthreads();

    int g0 = tid % 21;                  // (tid + it*512) % 21 steps by +8 mod 21

    #pragma unroll
    for (int i = 0; i < 4; ++i) {
        float* op = out + (size_t)(b * LL + i0 + i) * LC;
        const vf4* lyp_i = lyp4 + i * CC;
        int g = g0;
        #pragma unroll
        for (int it = 0; it < 11; ++it) {
            int idx = tid + it * 512;
            if (idx < NQ) {
                vf4 o = lzv[it] + lyp_i[g];
                __builtin_nontemporal_store(o, reinterpret_cast<vf4*>(op + (size_t)idx * 4));
            }
            g += 8; if (g >= 21) g -= 21;
        }
    }
}

extern "C" void kernel_launch(void* const* d_in, const int* in_sizes, int n_in,
                              void* d_out, int out_size, void* d_ws, size_t ws_size,
                              hipStream_t stream)
{
    const float* x     = (const float*)d_in[0];
    const float* dic   = (const float*)d_in[1];
    const float* prior = (const float*)d_in[2];
    const float* Wy_w  = (const float*)d_in[3];
    const float* Wy_b  = (const float*)d_in[4];
    const float* Wz_w  = (const float*)d_in[5];
    const float* Wz_b  = (const float*)d_in[6];
    const float* cs_w  = (const float*)d_in[7];
    const float* cs_b  = (const float*)d_in[8];
    float* out = (float*)d_out;

    float* ws = (float*)d_ws;
    float* zd = ws;                       // 420 floats
    float* M  = ws + 512;                 // 420 floats
    float* ly = ws + 1024;                // B*L*C = 86016 floats
    float* lz = ly + BB * LL * CC;        // 86016 floats

    k0_zdM <<<dim3(2 * KK * CC), dim3(64),  0, stream>>>(dic, Wz_w, Wz_b, cs_w, zd, M);
    k1_rows<<<dim3(BB * LL / 2), dim3(64),  0, stream>>>(x, prior, Wy_w, Wy_b, cs_w, cs_b,
                                                         zd, M, ly, lz);
    k2_outer<<<dim3(BB * LL / 4), dim3(512), 0, stream>>>(ly, lz, out);
}